// Round 1
// baseline (4997.283 us; speedup 1.0000x reference)
//
#include <hip/hip_runtime.h>
#include <hip/hip_fp16.h>
#include <math.h>

// Problem constants (fixed by reference setup_inputs)
constexpr int B_ = 16;
constexpr int D_ = 512;
constexpr int N_ = 2048;
constexpr int S_ = 15;     // N_SAMPLES
constexpr int TOPK = 16;

// GEMM tiling
constexpr int RT = 16;     // rows per block
constexpr int CT = 256;    // cols per chunk
constexpr int KT = 16;     // k-tile
constexpr int NCH = N_ / CT;     // 8 chunks
constexpr int KTILES = D_ / KT;  // 32

// ---------------------------------------------------------------------------
// Fused kernel: fp32 GEMM (logits) + per-row online softmax stats (m, logZ)
// + per-row top-16 candidates + optional fp16 logit dump / colsum accumulate.
// MODE 0: stats + top16 + fp16 logit store (path A)
// MODE 1: stats + top16 only            (path B pass 1)
// MODE 2: recompute GEMM, accumulate colsum via atomics (path B pass 2)
// ---------------------------------------------------------------------------
template <int MODE>
__global__ __launch_bounds__(256, 2) void fused_gemm(
    const float* __restrict__ srcE, const float* __restrict__ tgtE,
    float* __restrict__ cbuf,                 // [B][N]  (out for MODE0/1, in for MODE2)
    float* __restrict__ topv,                 // [B][N][TOPK]
    int*   __restrict__ topc,                 // [B][N][TOPK]
    __half* __restrict__ lhalf,               // [B][N][N] (MODE 0)
    float* __restrict__ colsum)               // [B][N]    (MODE 2)
{
    __shared__ float sA[D_ * RT];   // 32 KB: src columns, sA[d*16 + r]
    __shared__ float sB[KT * CT];   // 16 KB
    __shared__ float sC[RT * CT];   // 16 KB: logits tile
    __shared__ float crow[RT];

    const int tid = threadIdx.x;
    const int nrt = N_ / RT;             // 128 row-tiles per batch
    const int b  = blockIdx.x / nrt;
    const int rt = blockIdx.x % nrt;
    const int s0 = rt * RT;
    const float scale = 0.044194173824159216f;  // 1/sqrt(512)

    // load sA: src_embedding[b, d, s0..s0+15], vectorized float4 along s
    {
        const float* gs = srcE + (size_t)b * D_ * N_ + s0;
        for (int i = tid; i < (D_ * RT) / 4; i += 256) {
            int d  = i >> 2;
            int r4 = (i & 3) << 2;
            float4 v = *(const float4*)&gs[(size_t)d * N_ + r4];
            *(float4*)&sA[d * RT + r4] = v;
        }
    }
    if (MODE == 2) {
        if (tid < RT) crow[tid] = cbuf[b * N_ + s0 + tid];
    }

    const int tr = tid >> 6;   // wave id 0..3 -> row group
    const int tc = tid & 63;   // 0..63 -> col group
    const int srow = tid >> 4; // stats: row 0..15
    const int sq   = tid & 15; // stats: col-slice 0..15

    float m_loc = -1e30f, z_loc = 0.f;
    float tv[TOPK];
    int   tcid[TOPK];
    float tmin = -1e30f; int tminslot = 0, tmincol = 0x7fffffff;
    if (MODE != 2) {
        #pragma unroll
        for (int k = 0; k < TOPK; k++) { tv[k] = -1e30f; tcid[k] = 0x7fffffff; }
    }

    __syncthreads();

    for (int ch = 0; ch < NCH; ch++) {
        const int cbase = ch * CT;
        float acc[4][4];
        #pragma unroll
        for (int i = 0; i < 4; i++)
            #pragma unroll
            for (int j = 0; j < 4; j++) acc[i][j] = 0.f;

        for (int kt2 = 0; kt2 < KTILES; kt2++) {
            // stage sB = tgtE[b, kt2*16 .. +15, cbase .. +255]
            const float* gb = tgtE + (size_t)b * D_ * N_ + (size_t)(kt2 * KT) * N_ + cbase;
            #pragma unroll
            for (int it = 0; it < (KT * CT) / 4 / 256; it++) {  // 4 iters
                int i = it * 256 + tid;
                int kr = i >> 6;
                int c4 = (i & 63) << 2;
                *(float4*)&sB[kr * CT + c4] = *(const float4*)&gb[(size_t)kr * N_ + c4];
            }
            __syncthreads();
            #pragma unroll
            for (int kr = 0; kr < KT; kr++) {
                const float4 a4 = *(const float4*)&sA[(kt2 * KT + kr) * RT + tr * 4];
                const float4 b4 = *(const float4*)&sB[kr * CT + tc * 4];
                const float av_[4] = {a4.x, a4.y, a4.z, a4.w};
                const float bv_[4] = {b4.x, b4.y, b4.z, b4.w};
                #pragma unroll
                for (int i = 0; i < 4; i++)
                    #pragma unroll
                    for (int j = 0; j < 4; j++)
                        acc[i][j] += av_[i] * bv_[j];
            }
            __syncthreads();
        }

        // write logits tile to LDS (scaled)
        #pragma unroll
        for (int i = 0; i < 4; i++) {
            float4 v4 = make_float4(acc[i][0] * scale, acc[i][1] * scale,
                                    acc[i][2] * scale, acc[i][3] * scale);
            *(float4*)&sC[(tr * 4 + i) * CT + tc * 4] = v4;
        }
        __syncthreads();

        if (MODE != 2) {
            // per-thread online softmax stats + top16 over cols sq*16..+15
            #pragma unroll 1
            for (int j = 0; j < 16; j++) {
                float v = sC[srow * CT + sq * 16 + j];
                int col = cbase + sq * 16 + j;
                if (v > m_loc) { z_loc = z_loc * expf(m_loc - v) + 1.f; m_loc = v; }
                else           { z_loc += expf(v - m_loc); }
                bool ins = (v > tmin) || (v == tmin && col < tmincol);
                if (ins) {
                    #pragma unroll
                    for (int k = 0; k < TOPK; k++)
                        if (k == tminslot) { tv[k] = v; tcid[k] = col; }
                    tmin = tv[0]; tmincol = tcid[0]; tminslot = 0;
                    #pragma unroll
                    for (int k = 1; k < TOPK; k++) {
                        bool worse = (tv[k] < tmin) || (tv[k] == tmin && tcid[k] > tmincol);
                        if (worse) { tmin = tv[k]; tmincol = tcid[k]; tminslot = k; }
                    }
                }
            }
            if (MODE == 0) {
                // dump logits as fp16 (colsum pass input)
                for (int i = tid; i < RT * CT / 2; i += 256) {
                    int r  = i >> 7;
                    int cp = i & 127;
                    __half2 h2 = __floats2half2_rn(sC[r * CT + cp * 2], sC[r * CT + cp * 2 + 1]);
                    *(__half2*)&lhalf[(size_t)b * N_ * N_ + (size_t)(s0 + r) * N_ + cbase + cp * 2] = h2;
                }
            }
        } else {
            // colsum accumulation: thread owns column cbase+tid
            float partial = 0.f;
            #pragma unroll
            for (int r = 0; r < RT; r++)
                partial += expf(sC[r * CT + tid] - crow[r]);
            atomicAdd(&colsum[b * N_ + cbase + tid], partial);
        }
        __syncthreads();
    }

    if (MODE != 2) {
        // ---- merge m/z across the 16 threads of each row (reuse sB) ----
        float* mb = sB;
        float* zb = sB + 256;
        mb[tid] = m_loc;
        zb[tid] = z_loc;
        __syncthreads();
        if (tid < RT) {
            int row = tid;
            float M = -1e30f;
            for (int q = 0; q < 16; q++) M = fmaxf(M, mb[row * 16 + q]);
            float Z = 0.f;
            for (int q = 0; q < 16; q++) Z += zb[row * 16 + q] * expf(mb[row * 16 + q] - M);
            cbuf[b * N_ + s0 + row] = M + logf(Z);
        }
        __syncthreads();
        // ---- merge top16: dump all candidates to LDS ----
        float* vb  = sC;          // 16 rows x 256 candidates
        int*   cb2 = (int*)sB;
        #pragma unroll
        for (int k = 0; k < TOPK; k++) {
            vb[srow * 256 + sq * 16 + k]  = tv[k];
            cb2[srow * 256 + sq * 16 + k] = tcid[k];
        }
        __syncthreads();
        if (tid < RT) {
            int row = tid;
            float* ltv = sA + row * TOPK;                 // leader scratch in sA (free now)
            int*   ltc = (int*)(sA + RT * TOPK) + row * TOPK;
            for (int k = 0; k < TOPK; k++) { ltv[k] = -1e30f; ltc[k] = 0x7fffffff; }
            float lmin = -1e30f; int lslot = 0, lcol = 0x7fffffff;
            for (int i = 0; i < 256; i++) {
                float v = vb[row * 256 + i];
                int col = cb2[row * 256 + i];
                if (v > lmin || (v == lmin && col < lcol)) {
                    ltv[lslot] = v; ltc[lslot] = col;
                    lmin = ltv[0]; lcol = ltc[0]; lslot = 0;
                    for (int k = 1; k < TOPK; k++) {
                        if (ltv[k] < lmin || (ltv[k] == lmin && ltc[k] > lcol)) {
                            lmin = ltv[k]; lcol = ltc[k]; lslot = k;
                        }
                    }
                }
            }
            for (int k = 0; k < TOPK; k++) {
                topv[(size_t)(b * N_ + s0 + row) * TOPK + k] = ltv[k];
                topc[(size_t)(b * N_ + s0 + row) * TOPK + k] = ltc[k];
            }
        }
    }
}

// ---------------------------------------------------------------------------
// Path A colsum: colsum[b][t] = sum_s exp(l[s][t] - c[s]) from fp16 logits
// ---------------------------------------------------------------------------
__global__ void colsum_kernel(const __half* __restrict__ lhalf,
                              const float* __restrict__ cbuf,
                              float* __restrict__ colsum)
{
    __shared__ float cl[N_];
    const int b  = blockIdx.x >> 3;
    const int t0 = (blockIdx.x & 7) * 256;
    for (int i = threadIdx.x; i < N_; i += 256) cl[i] = cbuf[b * N_ + i];
    __syncthreads();
    const int t = t0 + threadIdx.x;
    const __half* base = lhalf + (size_t)b * N_ * N_ + t;
    float acc = 0.f;
    #pragma unroll 4
    for (int s = 0; s < N_; s++)
        acc += expf(__half2float(base[(size_t)s * N_]) - cl[s]);
    colsum[b * N_ + t] = acc;
}

// ---------------------------------------------------------------------------
// Greedy one-to-one matching (15 iters), one block per batch.
// Candidate value = logit - c[row] (log of softmax score; monotone).
// Tie-break: first row-major flat index (row, then col), matching jnp.argmax.
// ---------------------------------------------------------------------------
__global__ void match_kernel(const float* __restrict__ topv,
                             const int* __restrict__ topc,
                             const float* __restrict__ cbuf,
                             int* __restrict__ mrow, int* __restrict__ mcol)
{
    const int b = blockIdx.x;
    const int tid = threadIdx.x;
    __shared__ float cl[N_];
    __shared__ unsigned rowUsed[N_ / 32];
    __shared__ int supCol[S_];
    __shared__ int supCnt;
    __shared__ float rv[256];
    __shared__ int rr[256], rc[256];

    for (int i = tid; i < N_; i += 256) cl[i] = cbuf[b * N_ + i];
    for (int i = tid; i < N_ / 32; i += 256) rowUsed[i] = 0u;
    if (tid == 0) supCnt = 0;
    __syncthreads();

    for (int it = 0; it < S_; it++) {
        float bv = -1e30f; int br = 0x7fffffff, bc = 0x7fffffff;
        const int cnt = supCnt;
        for (int i = tid; i < N_ * TOPK; i += 256) {
            int row = i >> 4;
            if (rowUsed[row >> 5] & (1u << (row & 31))) continue;
            int col = topc[(size_t)(b * N_) * TOPK + i];
            bool sup = false;
            for (int k = 0; k < cnt; k++) sup = sup || (supCol[k] == col);
            if (sup) continue;
            float v = topv[(size_t)(b * N_) * TOPK + i] - cl[row];
            if (v > bv || (v == bv && (row < br || (row == br && col < bc)))) {
                bv = v; br = row; bc = col;
            }
        }
        rv[tid] = bv; rr[tid] = br; rc[tid] = bc;
        __syncthreads();
        for (int off = 128; off; off >>= 1) {
            if (tid < off) {
                float v2 = rv[tid + off]; int r2 = rr[tid + off], c2 = rc[tid + off];
                if (v2 > rv[tid] || (v2 == rv[tid] &&
                    (r2 < rr[tid] || (r2 == rr[tid] && c2 < rc[tid])))) {
                    rv[tid] = v2; rr[tid] = r2; rc[tid] = c2;
                }
            }
            __syncthreads();
        }
        if (tid == 0) {
            int row = rr[0], col = rc[0];
            mrow[b * S_ + it] = row;
            mcol[b * S_ + it] = col;
            rowUsed[row >> 5] |= 1u << (row & 31);
            supCol[supCnt] = col;
            supCnt = supCnt + 1;
        }
        __syncthreads();
    }
}

// ---------------------------------------------------------------------------
// Final: means, Kabsch (3x3 Jacobi SVD in fp64), R and t. One block per batch.
// ---------------------------------------------------------------------------
__global__ void finish_kernel(const float* __restrict__ src,   // [B][N][3]
                              const float* __restrict__ tgt,   // [B][N][3]
                              const float* __restrict__ colsum,
                              const int* __restrict__ mrow,
                              const int* __restrict__ mcol,
                              float* __restrict__ out)
{
    const int b = blockIdx.x;
    const int tid = threadIdx.x;
    __shared__ float red[256];
    __shared__ float res[6];  // src_mean[3], corr_mean[3]

    float ls[3] = {0, 0, 0}, lc[3] = {0, 0, 0};
    for (int n = tid; n < N_; n += 256) {
        float cs = colsum[b * N_ + n];
        #pragma unroll
        for (int j = 0; j < 3; j++) {
            ls[j] += src[(size_t)(b * N_ + n) * 3 + j];
            lc[j] += tgt[(size_t)(b * N_ + n) * 3 + j] * cs;
        }
    }
    for (int j = 0; j < 6; j++) {
        red[tid] = (j < 3) ? ls[j] : lc[j - 3];
        __syncthreads();
        for (int off = 128; off; off >>= 1) {
            if (tid < off) red[tid] += red[tid + off];
            __syncthreads();
        }
        if (tid == 0) res[j] = red[0] / (float)N_;
        __syncthreads();
    }

    if (tid == 0) {
        double ps[S_][3], pt[S_][3];
        double ms[3] = {0, 0, 0}, mt[3] = {0, 0, 0};
        for (int s = 0; s < S_; s++) {
            int r = mrow[b * S_ + s], c = mcol[b * S_ + s];
            for (int j = 0; j < 3; j++) {
                ps[s][j] = (double)src[(size_t)(b * N_ + r) * 3 + j];
                pt[s][j] = (double)tgt[(size_t)(b * N_ + c) * 3 + j];
                ms[j] += ps[s][j]; mt[j] += pt[s][j];
            }
        }
        for (int j = 0; j < 3; j++) { ms[j] /= S_; mt[j] /= S_; }
        double H[3][3] = {{0,0,0},{0,0,0},{0,0,0}};
        for (int s = 0; s < S_; s++)
            for (int i = 0; i < 3; i++)
                for (int j = 0; j < 3; j++)
                    H[i][j] += (ps[s][i] - ms[i]) * (pt[s][j] - mt[j]);

        // K = H^T H, Jacobi eigendecomposition -> V (right singular vectors)
        double A[3][3], Vv[3][3] = {{1,0,0},{0,1,0},{0,0,1}};
        for (int i = 0; i < 3; i++)
            for (int j = 0; j < 3; j++) {
                double acc = 0;
                for (int k = 0; k < 3; k++) acc += H[k][i] * H[k][j];
                A[i][j] = acc;
            }
        for (int sweep = 0; sweep < 30; sweep++) {
            double off = fabs(A[0][1]) + fabs(A[0][2]) + fabs(A[1][2]);
            if (off < 1e-30) break;
            for (int pair = 0; pair < 3; pair++) {
                int p = (pair == 2) ? 1 : 0;
                int q = (pair == 0) ? 1 : 2;
                double apq = A[p][q];
                if (fabs(apq) < 1e-300) continue;
                double theta = (A[q][q] - A[p][p]) / (2.0 * apq);
                double tt = ((theta >= 0) ? 1.0 : -1.0) / (fabs(theta) + sqrt(theta * theta + 1.0));
                double cc = 1.0 / sqrt(tt * tt + 1.0);
                double ssn = tt * cc;
                for (int k = 0; k < 3; k++) {
                    double akp = A[k][p], akq = A[k][q];
                    A[k][p] = cc * akp - ssn * akq;
                    A[k][q] = ssn * akp + cc * akq;
                }
                for (int k = 0; k < 3; k++) {
                    double apk = A[p][k], aqk = A[q][k];
                    A[p][k] = cc * apk - ssn * aqk;
                    A[q][k] = ssn * apk + cc * aqk;
                }
                for (int k = 0; k < 3; k++) {
                    double vkp = Vv[k][p], vkq = Vv[k][q];
                    Vv[k][p] = cc * vkp - ssn * vkq;
                    Vv[k][q] = ssn * vkp + cc * vkq;
                }
            }
        }
        double w[3] = {A[0][0], A[1][1], A[2][2]};
        // sort eigenpairs descending
        for (int a = 0; a < 2; a++)
            for (int b2 = a + 1; b2 < 3; b2++)
                if (w[b2] > w[a]) {
                    double tw = w[a]; w[a] = w[b2]; w[b2] = tw;
                    for (int k = 0; k < 3; k++) {
                        double tv_ = Vv[k][a]; Vv[k][a] = Vv[k][b2]; Vv[k][b2] = tv_;
                    }
                }
        // U columns: u_k = H v_k / sigma_k
        double U[3][3];
        for (int k = 0; k < 3; k++) {
            double u[3], nrm = 0;
            for (int i = 0; i < 3; i++) {
                double acc = 0;
                for (int j = 0; j < 3; j++) acc += H[i][j] * Vv[j][k];
                u[i] = acc; nrm += acc * acc;
            }
            nrm = sqrt(nrm);
            if (nrm < 1e-300) nrm = 1e-300;
            for (int i = 0; i < 3; i++) U[i][k] = u[i] / nrm;
        }
        // r = V U^T
        double r[3][3];
        for (int i = 0; i < 3; i++)
            for (int j = 0; j < 3; j++) {
                double acc = 0;
                for (int k = 0; k < 3; k++) acc += Vv[i][k] * U[j][k];
                r[i][j] = acc;
            }
        double det = r[0][0] * (r[1][1] * r[2][2] - r[1][2] * r[2][1])
                   - r[0][1] * (r[1][0] * r[2][2] - r[1][2] * r[2][0])
                   + r[0][2] * (r[1][0] * r[2][1] - r[1][1] * r[2][0]);
        if (det < 0.0) {
            for (int i = 0; i < 3; i++)
                for (int j = 0; j < 3; j++)
                    r[i][j] -= 2.0 * Vv[i][2] * U[j][2];
        }
        // t = -R @ src_mean + corr_mean
        double smean[3] = {(double)res[0], (double)res[1], (double)res[2]};
        double cmean[3] = {(double)res[3], (double)res[4], (double)res[5]};
        for (int i = 0; i < 3; i++)
            for (int j = 0; j < 3; j++)
                out[b * 9 + i * 3 + j] = (float)r[i][j];
        for (int i = 0; i < 3; i++) {
            double acc = cmean[i];
            for (int j = 0; j < 3; j++) acc -= r[i][j] * smean[j];
            out[B_ * 9 + b * 3 + i] = (float)acc;
        }
    }
}

// ---------------------------------------------------------------------------
extern "C" void kernel_launch(void* const* d_in, const int* in_sizes, int n_in,
                              void* d_out, int out_size, void* d_ws, size_t ws_size,
                              hipStream_t stream)
{
    const float* srcE = (const float*)d_in[0];
    const float* tgtE = (const float*)d_in[1];
    const float* src  = (const float*)d_in[2];
    const float* tgt  = (const float*)d_in[3];
    float* out = (float*)d_out;
    char* ws = (char*)d_ws;

    const size_t szLH   = (size_t)B_ * N_ * N_ * sizeof(__half);   // 128 MiB
    const size_t szC    = (size_t)B_ * N_ * sizeof(float);
    const size_t szTopV = (size_t)B_ * N_ * TOPK * sizeof(float);
    const size_t szTopC = (size_t)B_ * N_ * TOPK * sizeof(int);
    const size_t szCS   = (size_t)B_ * N_ * sizeof(float);
    const size_t szM    = 1024;
    const size_t needA  = szLH + szC + szTopV + szTopC + szCS + 2 * szM;

    const bool pathA = (ws_size >= needA);
    size_t base = pathA ? szLH : 0;
    __half* lhalf = (__half*)ws;
    float* cbuf   = (float*)(ws + base); base += szC;
    float* topv   = (float*)(ws + base); base += szTopV;
    int*   topc   = (int*)(ws + base);   base += szTopC;
    float* colsum = (float*)(ws + base); base += szCS;
    int*   mrow   = (int*)(ws + base);   base += szM;
    int*   mcol   = (int*)(ws + base);

    const int nblk = B_ * (N_ / RT);  // 2048

    if (pathA) {
        fused_gemm<0><<<nblk, 256, 0, stream>>>(srcE, tgtE, cbuf, topv, topc, lhalf, nullptr);
        colsum_kernel<<<B_ * 8, 256, 0, stream>>>(lhalf, cbuf, colsum);
    } else {
        fused_gemm<1><<<nblk, 256, 0, stream>>>(srcE, tgtE, cbuf, topv, topc, nullptr, nullptr);
        hipMemsetAsync(colsum, 0, szCS, stream);
        fused_gemm<2><<<nblk, 256, 0, stream>>>(srcE, tgtE, cbuf, nullptr, nullptr, nullptr, colsum);
    }
    match_kernel<<<B_, 256, 0, stream>>>(topv, topc, cbuf, mrow, mcol);
    finish_kernel<<<B_, 256, 0, stream>>>(src, tgt, colsum, mrow, mcol, out);
}

// Round 2
// 2339.064 us; speedup vs baseline: 2.1364x; 2.1364x over previous
//
#include <hip/hip_runtime.h>
#include <hip/hip_fp16.h>
#include <math.h>

constexpr int B_ = 16;
constexpr int D_ = 512;
constexpr int N_ = 2048;
constexpr int S_ = 15;
constexpr int TOPK = 16;

// GEMM tiling: block = 32 rows x 128 cols per chunk, 16 chunks, K=512 in 32 tiles of 16
constexpr int RT2 = 32;
constexpr int CT2 = 128;
constexpr int SCST = 132;   // sC row stride (pad 4)

// async global->LDS, 16 bytes per lane (dest = wave-uniform base + lane*16)
__device__ __forceinline__ void gl_lds16(const float* g, float* s) {
    __builtin_amdgcn_global_load_lds(
        (const __attribute__((address_space(1))) unsigned int*)g,
        (__attribute__((address_space(3))) unsigned int*)s,
        16, 0, 0);
}

// ---------------------------------------------------------------------------
// Fused fp32 GEMM: logits -> (E=exp(l) fp16 dump, per-row Z, per-row sorted
// top-16 adjusted by -log Z). Grid (64 rowblocks, 16 batches), 256 threads.
// ---------------------------------------------------------------------------
__global__ __launch_bounds__(256, 4) void gemm2(
    const float* __restrict__ srcE, const float* __restrict__ tgtE,
    float* __restrict__ rzbuf,            // [B][N] 1/Z
    float* __restrict__ topv,             // [B][N][16] sorted desc, adjusted (l - logZ)
    int*   __restrict__ topc,             // [B][N][16]
    __half* __restrict__ lhalf)           // [B][N][N] E = exp(l)
{
    __shared__ __align__(16) float smem[2 * 512 + 2 * 2048 + RT2 * SCST]; // 9344 floats
    float* sA = smem;            // 2 x [16k][32r]
    float* sB = smem + 1024;     // 2 x [16k][128c]
    float* sC = smem + 5120;     // [32][132]

    const int tid = threadIdx.x;
    const int b  = blockIdx.y;
    const int s0 = blockIdx.x * RT2;
    const int w  = tid >> 6, l = tid & 63;
    const int ty = tid >> 4, tx = tid & 15;      // rows ty*2..+1, cols tx*4 & 64+tx*4
    const int srow = tid >> 3, sq = tid & 7;     // stats: row srow, cols sq*16+j
    const float scale = 0.044194173824159216f;   // 1/sqrt(512)

    const float* gsrc = srcE + (size_t)b * D_ * N_;
    const float* gtgt = tgtE + (size_t)b * D_ * N_;

    float z_loc = 0.f;
    float tv[TOPK];
    int   tc16[TOPK];
    float tmin = -1e30f; int tminslot = 0, tmincol = 0x7fffffff;
    #pragma unroll
    for (int k = 0; k < TOPK; k++) { tv[k] = -1e30f; tc16[k] = 0x7fffffff; }

    // ---- staging helpers (async, no regs) ----
    auto stageA = [&](int bi, int k0) {
        if (w < 2) {
            int kr = w * 8 + (l >> 3);
            const float* g = gsrc + (size_t)(k0 + kr) * N_ + s0 + (l & 7) * 4;
            gl_lds16(g, &sA[bi * 512 + w * 256]);
        }
    };
    auto stageB = [&](int bi, int k0, int c0) {
        #pragma unroll
        for (int i = 0; i < 2; i++) {
            int kr = w * 4 + i * 2 + (l >> 5);
            const float* g = gtgt + (size_t)(k0 + kr) * N_ + c0 + (l & 31) * 4;
            gl_lds16(g, &sB[bi * 2048 + (w * 4 + i * 2) * 128]);
        }
    };

    stageA(0, 0);
    stageB(0, 0, 0);

    for (int ch = 0; ch < 16; ch++) {
        const int c0 = ch * CT2;
        float acc[2][8];
        #pragma unroll
        for (int i = 0; i < 2; i++)
            #pragma unroll
            for (int j = 0; j < 8; j++) acc[i][j] = 0.f;

        for (int kt = 0; kt < 32; kt++) {
            __syncthreads();                      // staged buffer (kt&1) ready
            if (kt < 31) { stageA((kt + 1) & 1, (kt + 1) * 16); stageB((kt + 1) & 1, (kt + 1) * 16, c0); }
            const float* A  = &sA[(kt & 1) * 512];
            const float* Bp = &sB[(kt & 1) * 2048];
            #pragma unroll
            for (int k = 0; k < 16; k++) {
                float2 a2 = *(const float2*)&A[k * 32 + ty * 2];
                float4 b0 = *(const float4*)&Bp[k * 128 + tx * 4];
                float4 b1 = *(const float4*)&Bp[k * 128 + 64 + tx * 4];
                acc[0][0] += a2.x * b0.x; acc[0][1] += a2.x * b0.y;
                acc[0][2] += a2.x * b0.z; acc[0][3] += a2.x * b0.w;
                acc[0][4] += a2.x * b1.x; acc[0][5] += a2.x * b1.y;
                acc[0][6] += a2.x * b1.z; acc[0][7] += a2.x * b1.w;
                acc[1][0] += a2.y * b0.x; acc[1][1] += a2.y * b0.y;
                acc[1][2] += a2.y * b0.z; acc[1][3] += a2.y * b0.w;
                acc[1][4] += a2.y * b1.x; acc[1][5] += a2.y * b1.y;
                acc[1][6] += a2.y * b1.z; acc[1][7] += a2.y * b1.w;
            }
        }

        // ---- epilogue: scaled logits to sC ----
        #pragma unroll
        for (int i = 0; i < 2; i++) {
            int r = ty * 2 + i;
            float4 v0 = make_float4(acc[i][0] * scale, acc[i][1] * scale,
                                    acc[i][2] * scale, acc[i][3] * scale);
            float4 v1 = make_float4(acc[i][4] * scale, acc[i][5] * scale,
                                    acc[i][6] * scale, acc[i][7] * scale);
            *(float4*)&sC[r * SCST + tx * 4] = v0;
            *(float4*)&sC[r * SCST + 64 + tx * 4] = v1;
        }
        __syncthreads();
        if (ch < 15) { stageA(0, 0); stageB(0, 0, c0 + CT2); } // prefetch next chunk kt0

        // ---- stats: row srow, cols sq*16+j (2-way banks = free) ----
        #pragma unroll 1
        for (int j = 0; j < 16; j++) {
            float v = sC[srow * SCST + sq * 16 + j];
            int c = c0 + sq * 16 + j;
            z_loc += expf(v);
            bool ins = (v > tmin) || (v == tmin && c < tmincol);
            if (ins) {
                #pragma unroll
                for (int k = 0; k < TOPK; k++)
                    if (k == tminslot) { tv[k] = v; tc16[k] = c; }
                tmin = tv[0]; tmincol = tc16[0]; tminslot = 0;
                #pragma unroll
                for (int k = 1; k < TOPK; k++) {
                    bool worse = (tv[k] < tmin) || (tv[k] == tmin && tc16[k] > tmincol);
                    if (worse) { tmin = tv[k]; tmincol = tc16[k]; tminslot = k; }
                }
            }
        }
        // ---- dump E = exp(l) as fp16 ----
        #pragma unroll 1
        for (int i = tid; i < RT2 * (CT2 / 2); i += 256) {
            int r = i >> 6, cp = i & 63;
            float e0 = expf(sC[r * SCST + cp * 2]);
            float e1 = expf(sC[r * SCST + cp * 2 + 1]);
            *(__half2*)&lhalf[((size_t)(b * N_ + s0 + r)) * N_ + c0 + cp * 2] =
                __floats2half2_rn(e0, e1);
        }
    }

    // ---- final merge: Z and sorted top-16 per row ----
    __syncthreads();
    float* vb = smem;                    // [16][256]
    int*   cb = (int*)(smem + 4096);     // [16][256]
    float* zb = smem + 8192;             // [256]
    zb[tid] = z_loc;
    #pragma unroll
    for (int k = 0; k < TOPK; k++) { vb[k * 256 + tid] = tv[k]; cb[k * 256 + tid] = tc16[k]; }
    __syncthreads();
    if (sq == 0) {
        float Z = 0.f;
        #pragma unroll
        for (int q = 0; q < 8; q++) Z += zb[tid + q];
        float lz = logf(Z);
        rzbuf[b * N_ + s0 + srow] = 1.0f / Z;
        // merge 8 partial lists (reuse tv/tc16 regs)
        tmin = -1e30f; tminslot = 0; tmincol = 0x7fffffff;
        #pragma unroll
        for (int k = 0; k < TOPK; k++) { tv[k] = -1e30f; tc16[k] = 0x7fffffff; }
        for (int q = 0; q < 8; q++) {
            #pragma unroll 1
            for (int k = 0; k < TOPK; k++) {
                float v = vb[k * 256 + tid + q];
                int c = cb[k * 256 + tid + q];
                bool ins = (v > tmin) || (v == tmin && c < tmincol);
                if (ins) {
                    #pragma unroll
                    for (int k2 = 0; k2 < TOPK; k2++)
                        if (k2 == tminslot) { tv[k2] = v; tc16[k2] = c; }
                    tmin = tv[0]; tmincol = tc16[0]; tminslot = 0;
                    #pragma unroll
                    for (int k2 = 1; k2 < TOPK; k2++) {
                        bool worse = (tv[k2] < tmin) || (tv[k2] == tmin && tc16[k2] > tmincol);
                        if (worse) { tmin = tv[k2]; tmincol = tc16[k2]; tminslot = k2; }
                    }
                }
            }
        }
        // emit sorted desc by (v, col asc), adjusted by -lz
        unsigned used = 0;
        size_t rowbase = ((size_t)b * N_ + s0 + srow) * TOPK;
        for (int o = 0; o < TOPK; o++) {
            float bvv = -1e31f; int bcc = 0x7fffffff; int bk = 0;
            #pragma unroll
            for (int k = 0; k < TOPK; k++) {
                bool u = (used >> k) & 1u;
                bool better = !u && ((tv[k] > bvv) || (tv[k] == bvv && tc16[k] < bcc));
                if (better) { bvv = tv[k]; bcc = tc16[k]; bk = k; }
            }
            used |= 1u << bk;
            topv[rowbase + o] = bvv - lz;
            topc[rowbase + o] = bcc;
        }
    }
}

// ---------------------------------------------------------------------------
// colsum[b][t] = sum_s E[s][t] * (1/Z_s). Grid (4 colchunks, 8 ssegs, 16 b).
// ---------------------------------------------------------------------------
__global__ __launch_bounds__(256) void colsum2(
    const __half* __restrict__ lhalf, const float* __restrict__ rzbuf,
    float* __restrict__ colsum)
{
    const int b = blockIdx.z, s0 = blockIdx.y * 256, t0 = blockIdx.x * 512;
    __shared__ float srz[256];
    srz[threadIdx.x] = rzbuf[b * N_ + s0 + threadIdx.x];
    __syncthreads();
    const int t = t0 + threadIdx.x * 2;
    const __half2* p = (const __half2*)(lhalf + ((size_t)(b * N_ + s0)) * N_ + t);
    float ax = 0.f, ay = 0.f;
    #pragma unroll 8
    for (int s = 0; s < 256; s++) {
        float2 f = __half22float2(p[(size_t)s * (N_ / 2)]);
        float r = srz[s];
        ax += f.x * r; ay += f.y * r;
    }
    atomicAdd(&colsum[b * N_ + t], ax);
    atomicAdd(&colsum[b * N_ + t + 1], ay);
}

// ---------------------------------------------------------------------------
// Greedy match: per-row current-best + rescan on collision. 1 block/batch.
// topv is sorted desc (tie: col asc) and pre-adjusted -> first valid = best.
// ---------------------------------------------------------------------------
__global__ __launch_bounds__(256) void match2(
    const float* __restrict__ topv, const int* __restrict__ topc,
    int* __restrict__ mrow, int* __restrict__ mcol)
{
    const int b = blockIdx.x, tid = threadIdx.x;
    __shared__ float bv[N_];
    __shared__ int bc[N_];
    __shared__ int sup[16];
    __shared__ float rv[256];
    __shared__ int rr[256];

    for (int r = tid; r < N_; r += 256) {
        bv[r] = topv[((size_t)b * N_ + r) * TOPK];
        bc[r] = topc[((size_t)b * N_ + r) * TOPK];
    }
    __syncthreads();

    for (int it = 0; it < S_; it++) {
        float mv = -1e30f; int mr = 0x7fffffff;
        #pragma unroll
        for (int j = 0; j < 8; j++) {
            int r = tid + j * 256;
            float v = bv[r];
            if (v > mv) { mv = v; mr = r; }   // ascending r: strict > keeps lowest row
        }
        rv[tid] = mv; rr[tid] = mr;
        __syncthreads();
        for (int off = 128; off; off >>= 1) {
            if (tid < off) {
                float v2 = rv[tid + off];
                if (v2 > rv[tid] || (v2 == rv[tid] && rr[tid + off] < rr[tid])) {
                    rv[tid] = v2; rr[tid] = rr[tid + off];
                }
            }
            __syncthreads();
        }
        if (tid == 0) {
            int R = rr[0]; int C = bc[R];
            mrow[b * S_ + it] = R; mcol[b * S_ + it] = C;
            sup[it] = C;
            bv[R] = -1e30f;
        }
        __syncthreads();
        const int C = sup[it];
        for (int r = tid; r < N_; r += 256) {
            if (bc[r] == C && bv[r] > -1e29f) {
                float nv = -1e30f; int nc = 0x7fffffff;
                const float* tvp = &topv[((size_t)b * N_ + r) * TOPK];
                const int* tcp = &topc[((size_t)b * N_ + r) * TOPK];
                for (int k = 0; k < TOPK; k++) {
                    int c2 = tcp[k];
                    bool bad = false;
                    for (int q = 0; q <= it; q++) bad = bad || (sup[q] == c2);
                    if (!bad) { nv = tvp[k]; nc = c2; break; }  // sorted: first valid = best
                }
                bv[r] = nv; bc[r] = nc;
            }
        }
        __syncthreads();
    }
}

// ---------------------------------------------------------------------------
// Final: means, Kabsch (3x3 Jacobi SVD in fp64), R and t. One block per batch.
// ---------------------------------------------------------------------------
__global__ void finish_kernel(const float* __restrict__ src,
                              const float* __restrict__ tgt,
                              const float* __restrict__ colsum,
                              const int* __restrict__ mrow,
                              const int* __restrict__ mcol,
                              float* __restrict__ out)
{
    const int b = blockIdx.x;
    const int tid = threadIdx.x;
    __shared__ float red[256];
    __shared__ float res[6];

    float ls[3] = {0, 0, 0}, lc[3] = {0, 0, 0};
    for (int n = tid; n < N_; n += 256) {
        float cs = colsum[b * N_ + n];
        #pragma unroll
        for (int j = 0; j < 3; j++) {
            ls[j] += src[(size_t)(b * N_ + n) * 3 + j];
            lc[j] += tgt[(size_t)(b * N_ + n) * 3 + j] * cs;
        }
    }
    for (int j = 0; j < 6; j++) {
        red[tid] = (j < 3) ? ls[j] : lc[j - 3];
        __syncthreads();
        for (int off = 128; off; off >>= 1) {
            if (tid < off) red[tid] += red[tid + off];
            __syncthreads();
        }
        if (tid == 0) res[j] = red[0] / (float)N_;
        __syncthreads();
    }

    if (tid == 0) {
        double ps[S_][3], pt[S_][3];
        double ms[3] = {0, 0, 0}, mt[3] = {0, 0, 0};
        for (int s = 0; s < S_; s++) {
            int r = mrow[b * S_ + s], c = mcol[b * S_ + s];
            for (int j = 0; j < 3; j++) {
                ps[s][j] = (double)src[(size_t)(b * N_ + r) * 3 + j];
                pt[s][j] = (double)tgt[(size_t)(b * N_ + c) * 3 + j];
                ms[j] += ps[s][j]; mt[j] += pt[s][j];
            }
        }
        for (int j = 0; j < 3; j++) { ms[j] /= S_; mt[j] /= S_; }
        double H[3][3] = {{0,0,0},{0,0,0},{0,0,0}};
        for (int s = 0; s < S_; s++)
            for (int i = 0; i < 3; i++)
                for (int j = 0; j < 3; j++)
                    H[i][j] += (ps[s][i] - ms[i]) * (pt[s][j] - mt[j]);

        double A[3][3], Vv[3][3] = {{1,0,0},{0,1,0},{0,0,1}};
        for (int i = 0; i < 3; i++)
            for (int j = 0; j < 3; j++) {
                double acc = 0;
                for (int k = 0; k < 3; k++) acc += H[k][i] * H[k][j];
                A[i][j] = acc;
            }
        for (int sweep = 0; sweep < 30; sweep++) {
            double off = fabs(A[0][1]) + fabs(A[0][2]) + fabs(A[1][2]);
            if (off < 1e-30) break;
            for (int pair = 0; pair < 3; pair++) {
                int p = (pair == 2) ? 1 : 0;
                int q = (pair == 0) ? 1 : 2;
                double apq = A[p][q];
                if (fabs(apq) < 1e-300) continue;
                double theta = (A[q][q] - A[p][p]) / (2.0 * apq);
                double tt = ((theta >= 0) ? 1.0 : -1.0) / (fabs(theta) + sqrt(theta * theta + 1.0));
                double cc = 1.0 / sqrt(tt * tt + 1.0);
                double ssn = tt * cc;
                for (int k = 0; k < 3; k++) {
                    double akp = A[k][p], akq = A[k][q];
                    A[k][p] = cc * akp - ssn * akq;
                    A[k][q] = ssn * akp + cc * akq;
                }
                for (int k = 0; k < 3; k++) {
                    double apk = A[p][k], aqk = A[q][k];
                    A[p][k] = cc * apk - ssn * aqk;
                    A[q][k] = ssn * apk + cc * aqk;
                }
                for (int k = 0; k < 3; k++) {
                    double vkp = Vv[k][p], vkq = Vv[k][q];
                    Vv[k][p] = cc * vkp - ssn * vkq;
                    Vv[k][q] = ssn * vkp + cc * vkq;
                }
            }
        }
        double wv[3] = {A[0][0], A[1][1], A[2][2]};
        for (int a = 0; a < 2; a++)
            for (int b2 = a + 1; b2 < 3; b2++)
                if (wv[b2] > wv[a]) {
                    double tw = wv[a]; wv[a] = wv[b2]; wv[b2] = tw;
                    for (int k = 0; k < 3; k++) {
                        double tv_ = Vv[k][a]; Vv[k][a] = Vv[k][b2]; Vv[k][b2] = tv_;
                    }
                }
        double U[3][3];
        for (int k = 0; k < 3; k++) {
            double u[3], nrm = 0;
            for (int i = 0; i < 3; i++) {
                double acc = 0;
                for (int j = 0; j < 3; j++) acc += H[i][j] * Vv[j][k];
                u[i] = acc; nrm += acc * acc;
            }
            nrm = sqrt(nrm);
            if (nrm < 1e-300) nrm = 1e-300;
            for (int i = 0; i < 3; i++) U[i][k] = u[i] / nrm;
        }
        double r[3][3];
        for (int i = 0; i < 3; i++)
            for (int j = 0; j < 3; j++) {
                double acc = 0;
                for (int k = 0; k < 3; k++) acc += Vv[i][k] * U[j][k];
                r[i][j] = acc;
            }
        double det = r[0][0] * (r[1][1] * r[2][2] - r[1][2] * r[2][1])
                   - r[0][1] * (r[1][0] * r[2][2] - r[1][2] * r[2][0])
                   + r[0][2] * (r[1][0] * r[2][1] - r[1][1] * r[2][0]);
        if (det < 0.0) {
            for (int i = 0; i < 3; i++)
                for (int j = 0; j < 3; j++)
                    r[i][j] -= 2.0 * Vv[i][2] * U[j][2];
        }
        double smean[3] = {(double)res[0], (double)res[1], (double)res[2]};
        double cmean[3] = {(double)res[3], (double)res[4], (double)res[5]};
        for (int i = 0; i < 3; i++)
            for (int j = 0; j < 3; j++)
                out[b * 9 + i * 3 + j] = (float)r[i][j];
        for (int i = 0; i < 3; i++) {
            double acc = cmean[i];
            for (int j = 0; j < 3; j++) acc -= r[i][j] * smean[j];
            out[B_ * 9 + b * 3 + i] = (float)acc;
        }
    }
}

// ---------------------------------------------------------------------------
extern "C" void kernel_launch(void* const* d_in, const int* in_sizes, int n_in,
                              void* d_out, int out_size, void* d_ws, size_t ws_size,
                              hipStream_t stream)
{
    const float* srcE = (const float*)d_in[0];
    const float* tgtE = (const float*)d_in[1];
    const float* src  = (const float*)d_in[2];
    const float* tgt  = (const float*)d_in[3];
    float* out = (float*)d_out;
    char* ws = (char*)d_ws;

    const size_t szLH = (size_t)B_ * N_ * N_ * sizeof(__half);   // 128 MiB
    size_t off = szLH;
    float* rzbuf  = (float*)(ws + off); off += (size_t)B_ * N_ * sizeof(float);
    float* topv   = (float*)(ws + off); off += (size_t)B_ * N_ * TOPK * sizeof(float);
    int*   topc   = (int*)(ws + off);   off += (size_t)B_ * N_ * TOPK * sizeof(int);
    float* colsum = (float*)(ws + off); off += (size_t)B_ * N_ * sizeof(float);
    int*   mrow   = (int*)(ws + off);   off += 1024;
    int*   mcol   = (int*)(ws + off);
    __half* lhalf = (__half*)ws;

    hipMemsetAsync(colsum, 0, (size_t)B_ * N_ * sizeof(float), stream);

    gemm2<<<dim3(N_ / RT2, B_), 256, 0, stream>>>(srcE, tgtE, rzbuf, topv, topc, lhalf);
    colsum2<<<dim3(N_ / 512, 8, B_), 256, 0, stream>>>(lhalf, rzbuf, colsum);
    match2<<<B_, 256, 0, stream>>>(topv, topc, mrow, mcol);
    finish_kernel<<<B_, 256, 0, stream>>>(src, tgt, colsum, mrow, mcol, out);
}

// Round 3
// 2042.999 us; speedup vs baseline: 2.4461x; 1.1449x over previous
//
#include <hip/hip_runtime.h>
#include <hip/hip_fp16.h>
#include <math.h>

constexpr int B_ = 16;
constexpr int D_ = 512;
constexpr int N_ = 2048;
constexpr int S_ = 15;
constexpr int TOPK = 16;

// GEMM tiling: block = 32 rows x 256 cols per chunk, 8 chunks, K=512 in 32 tiles of 16
constexpr int RT = 32;
constexpr int CT = 256;
constexpr int KT = 16;
constexpr int NCH = N_ / CT;    // 8
constexpr int NKT = D_ / KT;    // 32
constexpr int SCST = 260;       // sC row stride (pad 4)

// async global->LDS, 16 bytes per lane (dest = wave-uniform base + lane*16)
__device__ __forceinline__ void gl_lds16(const float* g, float* s) {
    __builtin_amdgcn_global_load_lds(
        (const __attribute__((address_space(1))) unsigned int*)g,
        (__attribute__((address_space(3))) unsigned int*)s,
        16, 0, 0);
}

// ---------------------------------------------------------------------------
// Fused fp32 GEMM: logits -> (E=exp(l) fp16 dump, per-row Z, per-row sorted
// top-16 adjusted by -log Z). Grid (64 rowblocks, 16 batches), 256 threads.
// Thread tile 4x8: rows ty*4..+3, cols tx*4 and 128+tx*4.
// ---------------------------------------------------------------------------
__global__ __launch_bounds__(256, 2) void gemm3(
    const float* __restrict__ srcE, const float* __restrict__ tgtE,
    float* __restrict__ rzbuf,            // [B][N] 1/Z
    float* __restrict__ topv,             // [B][N][16] sorted desc, adjusted (l - logZ)
    int*   __restrict__ topc,             // [B][N][16]
    __half* __restrict__ lhalf)           // [B][N][N] E = exp(l)
{
    __shared__ __align__(16) float smem[2 * KT * RT + 2 * KT * CT + RT * SCST]; // 17536 floats
    float* sA = smem;            // 2 x [16k][32r]
    float* sB = smem + 1024;     // 2 x [16k][256c]
    float* sC = smem + 9216;     // [32][260]

    const int tid = threadIdx.x;
    const int b  = blockIdx.y;
    const int s0 = blockIdx.x * RT;
    const int w  = tid >> 6, l = tid & 63;
    const int ty = tid >> 5, tx = tid & 31;      // GEMM: rows ty*4..+3, cols tx*4 / 128+tx*4
    const int srow = tid >> 3, sq = tid & 7;     // stats: row srow, cols sq*32..+31
    const float scale = 0.044194173824159216f;   // 1/sqrt(512)

    const float* gsrc = srcE + (size_t)b * D_ * N_;
    const float* gtgt = tgtE + (size_t)b * D_ * N_;

    float z_loc = 0.f;
    float tv[TOPK];
    int   tc16[TOPK];
    float tmin = -1e30f; int tminslot = 0, tmincol = 0x7fffffff;
    #pragma unroll
    for (int k = 0; k < TOPK; k++) { tv[k] = -1e30f; tc16[k] = 0x7fffffff; }

    // ---- async staging (no VGPR round trip) ----
    auto stageA = [&](int bi, int k0) {
        if (w < 2) {
            int kr = w * 8 + (l >> 3);
            gl_lds16(gsrc + (size_t)(k0 + kr) * N_ + s0 + (l & 7) * 4,
                     &sA[bi * 512 + w * 256]);
        }
    };
    auto stageB = [&](int bi, int k0, int c0) {
        #pragma unroll
        for (int i = 0; i < 4; i++) {
            int kr = w * 4 + i;
            gl_lds16(gtgt + (size_t)(k0 + kr) * N_ + c0 + l * 4,
                     &sB[bi * 4096 + kr * 256]);
        }
    };

    stageA(0, 0);
    stageB(0, 0, 0);

    for (int ch = 0; ch < NCH; ch++) {
        const int c0 = ch * CT;
        float acc[4][8];
        #pragma unroll
        for (int i = 0; i < 4; i++)
            #pragma unroll
            for (int j = 0; j < 8; j++) acc[i][j] = 0.f;

        for (int kt = 0; kt < NKT; kt++) {
            __syncthreads();                      // buffer (kt&1) staged & safe
            if (kt < NKT - 1) {
                stageA((kt + 1) & 1, (kt + 1) * KT);
                stageB((kt + 1) & 1, (kt + 1) * KT, c0);
            }
            const float* A  = &sA[(kt & 1) * 512];
            const float* Bp = &sB[(kt & 1) * 4096];
            #pragma unroll
            for (int k = 0; k < KT; k++) {
                float4 a4 = *(const float4*)&A[k * 32 + ty * 4];
                float4 b0 = *(const float4*)&Bp[k * 256 + tx * 4];
                float4 b1 = *(const float4*)&Bp[k * 256 + 128 + tx * 4];
                const float av[4] = {a4.x, a4.y, a4.z, a4.w};
                const float bv[8] = {b0.x, b0.y, b0.z, b0.w, b1.x, b1.y, b1.z, b1.w};
                #pragma unroll
                for (int i = 0; i < 4; i++)
                    #pragma unroll
                    for (int j = 0; j < 8; j++)
                        acc[i][j] += av[i] * bv[j];
            }
        }

        // ---- epilogue: scaled logits to sC ----
        #pragma unroll
        for (int i = 0; i < 4; i++) {
            int r = ty * 4 + i;
            *(float4*)&sC[r * SCST + tx * 4] =
                make_float4(acc[i][0] * scale, acc[i][1] * scale,
                            acc[i][2] * scale, acc[i][3] * scale);
            *(float4*)&sC[r * SCST + 128 + tx * 4] =
                make_float4(acc[i][4] * scale, acc[i][5] * scale,
                            acc[i][6] * scale, acc[i][7] * scale);
        }
        __syncthreads();
        if (ch < NCH - 1) { stageA(0, 0); stageB(0, 0, c0 + CT); } // prefetch next chunk kt0

        // ---- pass 1: stats + top16 (thread owns row srow, cols sq*32..+31) ----
        #pragma unroll 1
        for (int m = 0; m < 8; m++) {
            float4 v4 = *(const float4*)&sC[srow * SCST + sq * 32 + m * 4];
            const float vv[4] = {v4.x, v4.y, v4.z, v4.w};
            #pragma unroll
            for (int j = 0; j < 4; j++) {
                float v = vv[j];
                int c = c0 + sq * 32 + m * 4 + j;
                z_loc += expf(v);
                bool ins = (v > tmin) || (v == tmin && c < tmincol);
                if (ins) {
                    #pragma unroll
                    for (int k = 0; k < TOPK; k++)
                        if (k == tminslot) { tv[k] = v; tc16[k] = c; }
                    tmin = tv[0]; tmincol = tc16[0]; tminslot = 0;
                    #pragma unroll
                    for (int k = 1; k < TOPK; k++) {
                        bool worse = (tv[k] < tmin) || (tv[k] == tmin && tc16[k] > tmincol);
                        if (worse) { tmin = tv[k]; tmincol = tc16[k]; tminslot = k; }
                    }
                }
            }
        }

        // ---- pass 2: coalesced E=exp(l) fp16 dump (16B/lane contiguous) ----
        #pragma unroll 1
        for (int it = 0; it < 4; it++) {
            int flat = it * 2048 + tid * 8;
            int r = flat >> 8;
            int c = flat & 255;
            float4 fa = *(const float4*)&sC[r * SCST + c];
            float4 fb = *(const float4*)&sC[r * SCST + c + 4];
            __half2 h0 = __floats2half2_rn(expf(fa.x), expf(fa.y));
            __half2 h1 = __floats2half2_rn(expf(fa.z), expf(fa.w));
            __half2 h2 = __floats2half2_rn(expf(fb.x), expf(fb.y));
            __half2 h3 = __floats2half2_rn(expf(fb.z), expf(fb.w));
            struct alignas(16) H8 { __half2 a, b, c, d; };
            H8 h8 = {h0, h1, h2, h3};
            *(H8*)&lhalf[((size_t)(b * N_ + s0 + r)) * N_ + c0 + c] = h8;
        }
    }

    // ---- final merge: Z and sorted top-16 per row (8 partials per row) ----
    __syncthreads();
    float* vb = smem;                    // [16][256]
    int*   cb = (int*)(smem + 4096);     // [16][256]
    float* zb = smem + 8192;             // [256]
    zb[tid] = z_loc;
    #pragma unroll
    for (int k = 0; k < TOPK; k++) { vb[k * 256 + tid] = tv[k]; cb[k * 256 + tid] = tc16[k]; }
    __syncthreads();
    if (sq == 0) {
        float Z = 0.f;
        #pragma unroll
        for (int q = 0; q < 8; q++) Z += zb[tid + q];
        float lz = logf(Z);
        rzbuf[b * N_ + s0 + srow] = 1.0f / Z;
        tmin = -1e30f; tminslot = 0; tmincol = 0x7fffffff;
        #pragma unroll
        for (int k = 0; k < TOPK; k++) { tv[k] = -1e30f; tc16[k] = 0x7fffffff; }
        for (int q = 0; q < 8; q++) {
            #pragma unroll 1
            for (int k = 0; k < TOPK; k++) {
                float v = vb[k * 256 + tid + q];
                int c = cb[k * 256 + tid + q];
                bool ins = (v > tmin) || (v == tmin && c < tmincol);
                if (ins) {
                    #pragma unroll
                    for (int k2 = 0; k2 < TOPK; k2++)
                        if (k2 == tminslot) { tv[k2] = v; tc16[k2] = c; }
                    tmin = tv[0]; tmincol = tc16[0]; tminslot = 0;
                    #pragma unroll
                    for (int k2 = 1; k2 < TOPK; k2++) {
                        bool worse = (tv[k2] < tmin) || (tv[k2] == tmin && tc16[k2] > tmincol);
                        if (worse) { tmin = tv[k2]; tmincol = tc16[k2]; tminslot = k2; }
                    }
                }
            }
        }
        unsigned used = 0;
        size_t rowbase = ((size_t)b * N_ + s0 + srow) * TOPK;
        for (int o = 0; o < TOPK; o++) {
            float bvv = -1e31f; int bcc = 0x7fffffff; int bk = 0;
            #pragma unroll
            for (int k = 0; k < TOPK; k++) {
                bool u = (used >> k) & 1u;
                bool better = !u && ((tv[k] > bvv) || (tv[k] == bvv && tc16[k] < bcc));
                if (better) { bvv = tv[k]; bcc = tc16[k]; bk = k; }
            }
            used |= 1u << bk;
            topv[rowbase + o] = bvv - lz;
            topc[rowbase + o] = bcc;
        }
    }
}

// ---------------------------------------------------------------------------
// colsum[b][t] = sum_s E[s][t] * (1/Z_s). Grid (4 colchunks, 8 ssegs, 16 b).
// ---------------------------------------------------------------------------
__global__ __launch_bounds__(256) void colsum2(
    const __half* __restrict__ lhalf, const float* __restrict__ rzbuf,
    float* __restrict__ colsum)
{
    const int b = blockIdx.z, s0 = blockIdx.y * 256, t0 = blockIdx.x * 512;
    __shared__ float srz[256];
    srz[threadIdx.x] = rzbuf[b * N_ + s0 + threadIdx.x];
    __syncthreads();
    const int t = t0 + threadIdx.x * 2;
    const __half2* p = (const __half2*)(lhalf + ((size_t)(b * N_ + s0)) * N_ + t);
    float ax = 0.f, ay = 0.f;
    #pragma unroll 8
    for (int s = 0; s < 256; s++) {
        float2 f = __half22float2(p[(size_t)s * (N_ / 2)]);
        float r = srz[s];
        ax += f.x * r; ay += f.y * r;
    }
    atomicAdd(&colsum[b * N_ + t], ax);
    atomicAdd(&colsum[b * N_ + t + 1], ay);
}

// ---------------------------------------------------------------------------
// Greedy match: per-row current-best + rescan on collision. 1 block/batch.
// ---------------------------------------------------------------------------
__global__ __launch_bounds__(256) void match2(
    const float* __restrict__ topv, const int* __restrict__ topc,
    int* __restrict__ mrow, int* __restrict__ mcol)
{
    const int b = blockIdx.x, tid = threadIdx.x;
    __shared__ float bv[N_];
    __shared__ int bc[N_];
    __shared__ int sup[16];
    __shared__ float rv[256];
    __shared__ int rr[256];

    for (int r = tid; r < N_; r += 256) {
        bv[r] = topv[((size_t)b * N_ + r) * TOPK];
        bc[r] = topc[((size_t)b * N_ + r) * TOPK];
    }
    __syncthreads();

    for (int it = 0; it < S_; it++) {
        float mv = -1e30f; int mr = 0x7fffffff;
        #pragma unroll
        for (int j = 0; j < 8; j++) {
            int r = tid + j * 256;
            float v = bv[r];
            if (v > mv) { mv = v; mr = r; }
        }
        rv[tid] = mv; rr[tid] = mr;
        __syncthreads();
        for (int off = 128; off; off >>= 1) {
            if (tid < off) {
                float v2 = rv[tid + off];
                if (v2 > rv[tid] || (v2 == rv[tid] && rr[tid + off] < rr[tid])) {
                    rv[tid] = v2; rr[tid] = rr[tid + off];
                }
            }
            __syncthreads();
        }
        if (tid == 0) {
            int R = rr[0]; int C = bc[R];
            mrow[b * S_ + it] = R; mcol[b * S_ + it] = C;
            sup[it] = C;
            bv[R] = -1e30f;
        }
        __syncthreads();
        const int C = sup[it];
        for (int r = tid; r < N_; r += 256) {
            if (bc[r] == C && bv[r] > -1e29f) {
                float nv = -1e30f; int nc = 0x7fffffff;
                const float* tvp = &topv[((size_t)b * N_ + r) * TOPK];
                const int* tcp = &topc[((size_t)b * N_ + r) * TOPK];
                for (int k = 0; k < TOPK; k++) {
                    int c2 = tcp[k];
                    bool bad = false;
                    for (int q = 0; q <= it; q++) bad = bad || (sup[q] == c2);
                    if (!bad) { nv = tvp[k]; nc = c2; break; }
                }
                bv[r] = nv; bc[r] = nc;
            }
        }
        __syncthreads();
    }
}

// ---------------------------------------------------------------------------
// Final: means, Kabsch (3x3 Jacobi SVD in fp64), R and t. One block per batch.
// ---------------------------------------------------------------------------
__global__ void finish_kernel(const float* __restrict__ src,
                              const float* __restrict__ tgt,
                              const float* __restrict__ colsum,
                              const int* __restrict__ mrow,
                              const int* __restrict__ mcol,
                              float* __restrict__ out)
{
    const int b = blockIdx.x;
    const int tid = threadIdx.x;
    __shared__ float red[256];
    __shared__ float res[6];

    float ls[3] = {0, 0, 0}, lc[3] = {0, 0, 0};
    for (int n = tid; n < N_; n += 256) {
        float cs = colsum[b * N_ + n];
        #pragma unroll
        for (int j = 0; j < 3; j++) {
            ls[j] += src[(size_t)(b * N_ + n) * 3 + j];
            lc[j] += tgt[(size_t)(b * N_ + n) * 3 + j] * cs;
        }
    }
    for (int j = 0; j < 6; j++) {
        red[tid] = (j < 3) ? ls[j] : lc[j - 3];
        __syncthreads();
        for (int off = 128; off; off >>= 1) {
            if (tid < off) red[tid] += red[tid + off];
            __syncthreads();
        }
        if (tid == 0) res[j] = red[0] / (float)N_;
        __syncthreads();
    }

    if (tid == 0) {
        double ps[S_][3], pt[S_][3];
        double ms[3] = {0, 0, 0}, mt[3] = {0, 0, 0};
        for (int s = 0; s < S_; s++) {
            int r = mrow[b * S_ + s], c = mcol[b * S_ + s];
            for (int j = 0; j < 3; j++) {
                ps[s][j] = (double)src[(size_t)(b * N_ + r) * 3 + j];
                pt[s][j] = (double)tgt[(size_t)(b * N_ + c) * 3 + j];
                ms[j] += ps[s][j]; mt[j] += pt[s][j];
            }
        }
        for (int j = 0; j < 3; j++) { ms[j] /= S_; mt[j] /= S_; }
        double H[3][3] = {{0,0,0},{0,0,0},{0,0,0}};
        for (int s = 0; s < S_; s++)
            for (int i = 0; i < 3; i++)
                for (int j = 0; j < 3; j++)
                    H[i][j] += (ps[s][i] - ms[i]) * (pt[s][j] - mt[j]);

        double A[3][3], Vv[3][3] = {{1,0,0},{0,1,0},{0,0,1}};
        for (int i = 0; i < 3; i++)
            for (int j = 0; j < 3; j++) {
                double acc = 0;
                for (int k = 0; k < 3; k++) acc += H[k][i] * H[k][j];
                A[i][j] = acc;
            }
        for (int sweep = 0; sweep < 30; sweep++) {
            double off = fabs(A[0][1]) + fabs(A[0][2]) + fabs(A[1][2]);
            if (off < 1e-30) break;
            for (int pair = 0; pair < 3; pair++) {
                int p = (pair == 2) ? 1 : 0;
                int q = (pair == 0) ? 1 : 2;
                double apq = A[p][q];
                if (fabs(apq) < 1e-300) continue;
                double theta = (A[q][q] - A[p][p]) / (2.0 * apq);
                double tt = ((theta >= 0) ? 1.0 : -1.0) / (fabs(theta) + sqrt(theta * theta + 1.0));
                double cc = 1.0 / sqrt(tt * tt + 1.0);
                double ssn = tt * cc;
                for (int k = 0; k < 3; k++) {
                    double akp = A[k][p], akq = A[k][q];
                    A[k][p] = cc * akp - ssn * akq;
                    A[k][q] = ssn * akp + cc * akq;
                }
                for (int k = 0; k < 3; k++) {
                    double apk = A[p][k], aqk = A[q][k];
                    A[p][k] = cc * apk - ssn * aqk;
                    A[q][k] = ssn * apk + cc * aqk;
                }
                for (int k = 0; k < 3; k++) {
                    double vkp = Vv[k][p], vkq = Vv[k][q];
                    Vv[k][p] = cc * vkp - ssn * vkq;
                    Vv[k][q] = ssn * vkp + cc * vkq;
                }
            }
        }
        double wv[3] = {A[0][0], A[1][1], A[2][2]};
        for (int a = 0; a < 2; a++)
            for (int b2 = a + 1; b2 < 3; b2++)
                if (wv[b2] > wv[a]) {
                    double tw = wv[a]; wv[a] = wv[b2]; wv[b2] = tw;
                    for (int k = 0; k < 3; k++) {
                        double tv_ = Vv[k][a]; Vv[k][a] = Vv[k][b2]; Vv[k][b2] = tv_;
                    }
                }
        double U[3][3];
        for (int k = 0; k < 3; k++) {
            double u[3], nrm = 0;
            for (int i = 0; i < 3; i++) {
                double acc = 0;
                for (int j = 0; j < 3; j++) acc += H[i][j] * Vv[j][k];
                u[i] = acc; nrm += acc * acc;
            }
            nrm = sqrt(nrm);
            if (nrm < 1e-300) nrm = 1e-300;
            for (int i = 0; i < 3; i++) U[i][k] = u[i] / nrm;
        }
        double r[3][3];
        for (int i = 0; i < 3; i++)
            for (int j = 0; j < 3; j++) {
                double acc = 0;
                for (int k = 0; k < 3; k++) acc += Vv[i][k] * U[j][k];
                r[i][j] = acc;
            }
        double det = r[0][0] * (r[1][1] * r[2][2] - r[1][2] * r[2][1])
                   - r[0][1] * (r[1][0] * r[2][2] - r[1][2] * r[2][0])
                   + r[0][2] * (r[1][0] * r[2][1] - r[1][1] * r[2][0]);
        if (det < 0.0) {
            for (int i = 0; i < 3; i++)
                for (int j = 0; j < 3; j++)
                    r[i][j] -= 2.0 * Vv[i][2] * U[j][2];
        }
        double smean[3] = {(double)res[0], (double)res[1], (double)res[2]};
        double cmean[3] = {(double)res[3], (double)res[4], (double)res[5]};
        for (int i = 0; i < 3; i++)
            for (int j = 0; j < 3; j++)
                out[b * 9 + i * 3 + j] = (float)r[i][j];
        for (int i = 0; i < 3; i++) {
            double acc = cmean[i];
            for (int j = 0; j < 3; j++) acc -= r[i][j] * smean[j];
            out[B_ * 9 + b * 3 + i] = (float)acc;
        }
    }
}

// ---------------------------------------------------------------------------
extern "C" void kernel_launch(void* const* d_in, const int* in_sizes, int n_in,
                              void* d_out, int out_size, void* d_ws, size_t ws_size,
                              hipStream_t stream)
{
    const float* srcE = (const float*)d_in[0];
    const float* tgtE = (const float*)d_in[1];
    const float* src  = (const float*)d_in[2];
    const float* tgt  = (const float*)d_in[3];
    float* out = (float*)d_out;
    char* ws = (char*)d_ws;

    const size_t szLH = (size_t)B_ * N_ * N_ * sizeof(__half);   // 128 MiB
    size_t off = szLH;
    float* rzbuf  = (float*)(ws + off); off += (size_t)B_ * N_ * sizeof(float);
    float* topv   = (float*)(ws + off); off += (size_t)B_ * N_ * TOPK * sizeof(float);
    int*   topc   = (int*)(ws + off);   off += (size_t)B_ * N_ * TOPK * sizeof(int);
    float* colsum = (float*)(ws + off); off += (size_t)B_ * N_ * sizeof(float);
    int*   mrow   = (int*)(ws + off);   off += 1024;
    int*   mcol   = (int*)(ws + off);
    __half* lhalf = (__half*)ws;

    hipMemsetAsync(colsum, 0, (size_t)B_ * N_ * sizeof(float), stream);

    gemm3<<<dim3(N_ / RT, B_), 256, 0, stream>>>(srcE, tgtE, rzbuf, topv, topc, lhalf);
    colsum2<<<dim3(N_ / 512, 8, B_), 256, 0, stream>>>(lhalf, rzbuf, colsum);
    match2<<<B_, 256, 0, stream>>>(topv, topc, mrow, mcol);
    finish_kernel<<<B_, 256, 0, stream>>>(src, tgt, colsum, mrow, mcol, out);
}